// Round 7
// baseline (47.737 us; speedup 1.0000x reference)
//
#include <hip/hip_runtime.h>
#include <math.h>

#define V   50000
#define DIM 128
#define BB  512
#define LQ  30
#define RD  200
#define KN  21
#define STRIPS 7   // 7 strips x 32 doc cols = 224 >= 200

typedef unsigned short ushort_t;
typedef __attribute__((ext_vector_type(8))) short bf16x8;   // 8 bf16 = 4 VGPRs
typedef __attribute__((ext_vector_type(4))) float f32x4;

#if __has_builtin(__builtin_amdgcn_exp2f)
#define EXP2F(x) __builtin_amdgcn_exp2f(x)
#else
#define EXP2F(x) __expf((x) * 0.69314718f)
#endif

#define ALPHA 72.1347520f       // 50 * log2(e)
#define E10   22026.4657948f    // 2^(0.2*ALPHA) = e^10

static __device__ __forceinline__ ushort_t f2bf(float x) {
    unsigned u = __builtin_bit_cast(unsigned, x);
    return (ushort_t)((u + 0x7FFFu + ((u >> 16) & 1u)) >> 16);   // RNE
}
static __device__ __forceinline__ bf16x8 as_frag(int4 v) {
    return __builtin_bit_cast(bf16x8, v);
}

// ------------- kernel 1: L2-normalize -> bf16 (hi only), float4 loads -------------
__global__ __launch_bounds__(256) void knrm_norm(const float* __restrict__ emb,
                                                 ushort_t* __restrict__ nh) {
    int row = blockIdx.x * 8 + (threadIdx.x >> 5);   // V divisible by 8
    int c4  = (threadIdx.x & 31) * 4;
    const float4 v = *reinterpret_cast<const float4*>(emb + (size_t)row * DIM + c4);
    float ss = v.x * v.x + v.y * v.y + v.z * v.z + v.w * v.w;
#pragma unroll
    for (int off = 1; off < 32; off <<= 1) ss += __shfl_xor(ss, off);
    float inv = 1.0f / fmaxf(sqrtf(ss), 1e-12f);
    uint2 o;
    o.x = (unsigned)f2bf(v.x * inv) | ((unsigned)f2bf(v.y * inv) << 16);
    o.y = (unsigned)f2bf(v.z * inv) | ((unsigned)f2bf(v.w * inv) << 16);
    *reinterpret_cast<uint2*>(nh + (size_t)row * DIM + c4) = o;
}

// Two-leg geometric Gaussian bank (verified R6): K_k(m) = B_j * t_j,
// t_{j+1} = t_j * u, B_j applied at the finish stage. Exact kernel
// (mu=1, sigma=1e-3) = integer token equality count in ks[20].
// Invalid cols: m = -16 -> every term underflows to exact 0.
static __device__ __forceinline__ void bank4_geo(f32x4 acc, int4 dt, int qt,
                                                 int colbase, float* ks) {
    const float mv[4] = {acc[0], acc[1], acc[2], acc[3]};
    const int   dv[4] = {dt.x, dt.y, dt.z, dt.w};
#pragma unroll
    for (int i = 0; i < 4; ++i) {
        float m  = (colbase + i < RD) ? mv[i] : -16.0f;
        float dA = m + 0.5f, dB = m - 0.5f;
        float tA = EXP2F(-ALPHA * dA * (dA + 0.9f));   // leg A start (k=0)
        float tB = EXP2F(-ALPHA * dB * (dB + 0.9f));   // leg B start (k=10)
        float uB = EXP2F(14.4269504f * dB);            // 2^(0.2*ALPHA*dB)
        float uA = uB * E10;
        ks[20] += (dv[i] == qt) ? 1.0f : 0.0f;
#pragma unroll
        for (int k = 0; k < 10; ++k) {
            ks[k]      += tA; tA *= uA;
            ks[10 + k] += tB; tB *= uB;
        }
    }
}

static __device__ __forceinline__ void load_frag4(const ushort_t* base, int4* f) {
    f[0] = *reinterpret_cast<const int4*>(base);
    f[1] = *reinterpret_cast<const int4*>(base + 32);
    f[2] = *reinterpret_cast<const int4*>(base + 64);
    f[3] = *reinterpret_cast<const int4*>(base + 96);
}

// ------------- kernel 2: barrier-free swapped-operand KNRM -------------
// 1024 blocks (pair*b) x 448 threads (7 waves). wave = strip of 32 doc cols.
// mfma(D_frag, Q_frag): C/D col = lane&15 = QUERY row -> each lane's accs
// belong to one q-row; bank consumes accumulators directly (no P LDS, no
// compute barriers). Rowgroups sequenced to cap live ksum regs at 42.
__global__ __launch_bounds__(448) void knrm_main(
    const ushort_t* __restrict__ nh, const float* __restrict__ W,
    const int* __restrict__ q1, const int* __restrict__ d1,
    const int* __restrict__ q2, const int* __restrict__ d2,
    float* __restrict__ logits)
{
    __shared__ int   sQtok[32];
    __shared__ int   sDtok[STRIPS * 32];           // 224
    __shared__ float kred[STRIPS][32][KN];         // 18816 B

    const int pb = blockIdx.x;
    const int pair = pb >> 9, b = pb & 511;
    const int* qind = (pair ? q2 : q1) + b * LQ;
    const int* dind = (pair ? d2 : d1) + b * RD;

    const int tid = threadIdx.x;
    const int lane = tid & 63, wave = tid >> 6;    // wave = strip
    const int r = lane & 15, g = lane >> 4;

    if (tid < 32) sQtok[tid] = (tid < LQ) ? qind[tid] : -2;
    if (tid < STRIPS * 32) sDtok[tid] = (tid < RD) ? dind[tid] : -1;

    // ---- gathers: Q rows r / 16+r, D rows strip*32 + r / +16 ----
    const int qiA = qind[r];
    const int qiB = qind[(16 + r) < LQ ? (16 + r) : LQ - 1];
    const int dcA = wave * 32 + r, dcB = dcA + 16;
    const int diA = dind[dcA < RD ? dcA : RD - 1];
    const int diB = dind[dcB < RD ? dcB : RD - 1];

    int4 qa[4], qb[4], da[4], db[4];
    load_frag4(nh + (size_t)qiA * DIM + g * 8, qa);
    load_frag4(nh + (size_t)qiB * DIM + g * 8, qb);
    load_frag4(nh + (size_t)diA * DIM + g * 8, da);
    load_frag4(nh + (size_t)diB * DIM + g * 8, db);

    // ---- 16 MFMAs: acc rows = D cols (g*4+j), cols = Q rows (r) ----
    f32x4 a00 = {0.f,0.f,0.f,0.f}, a01 = {0.f,0.f,0.f,0.f};
    f32x4 a10 = {0.f,0.f,0.f,0.f}, a11 = {0.f,0.f,0.f,0.f};
#pragma unroll
    for (int ks = 0; ks < 4; ++ks) {
        bf16x8 fa = as_frag(da[ks]), fb = as_frag(db[ks]);
        bf16x8 f0 = as_frag(qa[ks]), f1 = as_frag(qb[ks]);
        a00 = __builtin_amdgcn_mfma_f32_16x16x32_bf16(fa, f0, a00, 0, 0, 0);
        a01 = __builtin_amdgcn_mfma_f32_16x16x32_bf16(fa, f1, a01, 0, 0, 0);
        a10 = __builtin_amdgcn_mfma_f32_16x16x32_bf16(fb, f0, a10, 0, 0, 0);
        a11 = __builtin_amdgcn_mfma_f32_16x16x32_bf16(fb, f1, a11, 0, 0, 0);
    }

    __syncthreads();   // token tables ready (only barrier before finish)

    const int4* sDtok4 = (const int4*)sDtok;
    const int4 dtA = sDtok4[wave * 8 + g];         // cols strip*32 + g*4 + j
    const int4 dtB = sDtok4[wave * 8 + 4 + g];     // +16
    const int qt0 = sQtok[r], qt1 = sQtok[16 + r];
    const int colA = wave * 32 + g * 4, colB = colA + 16;

    // ---- rowgroup 0 (q rows 0..15): bank -> reduce over g -> LDS ----
    {
        float ks0[KN];
#pragma unroll
        for (int k = 0; k < KN; ++k) ks0[k] = 0.0f;
        bank4_geo(a00, dtA, qt0, colA, ks0);
        bank4_geo(a10, dtB, qt0, colB, ks0);
#pragma unroll
        for (int k = 0; k < KN; ++k) {
            float v = ks0[k];
            v += __shfl_xor(v, 16);
            v += __shfl_xor(v, 32);
            ks0[k] = v;
        }
        if (lane < 16) {
#pragma unroll
            for (int k = 0; k < KN; ++k) kred[wave][r][k] = ks0[k];
        }
    }
    // ---- rowgroup 1 (q rows 16..31; 30,31 computed but never read) ----
    {
        float ks1[KN];
#pragma unroll
        for (int k = 0; k < KN; ++k) ks1[k] = 0.0f;
        bank4_geo(a01, dtA, qt1, colA, ks1);
        bank4_geo(a11, dtB, qt1, colB, ks1);
#pragma unroll
        for (int k = 0; k < KN; ++k) {
            float v = ks1[k];
            v += __shfl_xor(v, 16);
            v += __shfl_xor(v, 32);
            ks1[k] = v;
        }
        if (lane < 16) {
#pragma unroll
            for (int k = 0; k < KN; ++k) kred[wave][16 + r][k] = ks1[k];
        }
    }
    __syncthreads();

    // ---- finish: combine strips, B_j scale, log1p, W-dot, row reduce ----
    if (tid < 32) {
        float part = 0.0f;
        if (tid < LQ) {
#pragma unroll
            for (int k = 0; k < KN; ++k) {
                float s = 0.0f;
#pragma unroll
                for (int st = 0; st < STRIPS; ++st) s += kred[st][tid][k];
                float sc = 1.0f;
                if (k < 20) {
                    float j = (float)((k < 10) ? k : k - 10) - 4.5f;
                    sc = EXP2F(-0.721347520f * j * j);   // B_j (compile-time)
                }
                part += W[k] * log1pf(sc * s);
            }
        }
        part += __shfl_xor(part, 1);
        part += __shfl_xor(part, 2);
        part += __shfl_xor(part, 4);
        part += __shfl_xor(part, 8);
        part += __shfl_xor(part, 16);
        if (tid == 0) logits[pair * BB + b] = part;   // bias cancels in diff
    }
}

// ------------- kernel 3: sigmoid of logit difference -------------
__global__ void knrm_final(const float* __restrict__ logits, float* __restrict__ out) {
    int i = blockIdx.x * blockDim.x + threadIdx.x;
    if (i < BB) {
        float x = logits[i] - logits[BB + i];
        out[i] = 1.0f / (1.0f + expf(-x));
    }
}

extern "C" void kernel_launch(void* const* d_in, const int* in_sizes, int n_in,
                              void* d_out, int out_size, void* d_ws, size_t ws_size,
                              hipStream_t stream) {
    const float* emb = (const float*)d_in[0];
    const float* W   = (const float*)d_in[1];
    const int* q1    = (const int*)d_in[3];
    const int* dd1   = (const int*)d_in[4];
    const int* q2    = (const int*)d_in[5];
    const int* dd2   = (const int*)d_in[6];

    ushort_t* nh  = (ushort_t*)d_ws;                 // V*128 bf16 = 12.8 MB
    float* logits = (float*)(nh + (size_t)V * DIM);  // 1024 floats

    knrm_norm<<<V / 8, 256, 0, stream>>>(emb, nh);
    knrm_main<<<1024, 448, 0, stream>>>(nh, W, q1, dd1, q2, dd2, logits);
    knrm_final<<<2, 256, 0, stream>>>(logits, (float*)d_out);
}

// Round 8
// 46.387 us; speedup vs baseline: 1.0291x; 1.0291x over previous
//
#include <hip/hip_runtime.h>
#include <math.h>

#define V   50000
#define DIM 128
#define BB  512
#define LQ  30
#define RD  200
#define KN  21

typedef unsigned short ushort_t;
typedef __attribute__((ext_vector_type(8))) short bf16x8;   // 8 bf16 = 4 VGPRs
typedef __attribute__((ext_vector_type(4))) float f32x4;
typedef __attribute__((ext_vector_type(2))) float f32x2;    // -> v_pk_*_f32

#if __has_builtin(__builtin_amdgcn_exp2f)
#define EXP2F(x) __builtin_amdgcn_exp2f(x)
#else
#define EXP2F(x) __expf((x) * 0.69314718f)
#endif

#define ALPHA 72.1347520f       // 50 * log2(e)
#define E10   22026.4657948f    // 2^(0.2*ALPHA) = e^10

static __device__ __forceinline__ ushort_t f2bf(float x) {
    unsigned u = __builtin_bit_cast(unsigned, x);
    return (ushort_t)((u + 0x7FFFu + ((u >> 16) & 1u)) >> 16);   // RNE
}
static __device__ __forceinline__ bf16x8 as_frag(int4 v) {
    return __builtin_bit_cast(bf16x8, v);
}
static __device__ __forceinline__ void load_frag4(const ushort_t* base, int4* f) {
    f[0] = *reinterpret_cast<const int4*>(base);
    f[1] = *reinterpret_cast<const int4*>(base + 32);
    f[2] = *reinterpret_cast<const int4*>(base + 64);
    f[3] = *reinterpret_cast<const int4*>(base + 96);
}

// ------------- kernel 1: L2-normalize -> bf16 (hi only), float4 loads -------------
__global__ __launch_bounds__(256) void knrm_norm(const float* __restrict__ emb,
                                                 ushort_t* __restrict__ nh) {
    int row = blockIdx.x * 8 + (threadIdx.x >> 5);   // V divisible by 8
    int c4  = (threadIdx.x & 31) * 4;
    const float4 v = *reinterpret_cast<const float4*>(emb + (size_t)row * DIM + c4);
    float ss = v.x * v.x + v.y * v.y + v.z * v.z + v.w * v.w;
#pragma unroll
    for (int off = 1; off < 32; off <<= 1) ss += __shfl_xor(ss, off);
    float inv = 1.0f / fmaxf(sqrtf(ss), 1e-12f);
    uint2 o;
    o.x = (unsigned)f2bf(v.x * inv) | ((unsigned)f2bf(v.y * inv) << 16);
    o.y = (unsigned)f2bf(v.z * inv) | ((unsigned)f2bf(v.w * inv) << 16);
    *reinterpret_cast<uint2*>(nh + (size_t)row * DIM + c4) = o;
}

// Two-leg geometric Gaussian bank (verified R6/R7), packed-f32 + 4-way tree.
// x-component = leg A (kernels 0..9, center mu=-0.5), y = leg B (10..19, +0.5).
// B_j constants folded in at the finish stage. Exact kernel (mu=1, sigma=1e-3)
// = integer token equality count. Invalid cols: m=-16 -> all terms exact 0.
static __device__ __forceinline__ void bank4_pk(f32x4 acc, int4 dt, int qt,
                                                int colbase, f32x2* ks2, float& cnt) {
    const float mv[4] = {acc[0], acc[1], acc[2], acc[3]};
    const int   dv[4] = {dt.x, dt.y, dt.z, dt.w};
    f32x2 t[4], u[4];
#pragma unroll
    for (int i = 0; i < 4; ++i) {
        float m  = (colbase + i < RD) ? mv[i] : -16.0f;
        float dA = m + 0.5f, dB = m - 0.5f;
        float tA = EXP2F(-ALPHA * dA * (dA + 0.9f));   // leg A start (k=0)
        float tB = EXP2F(-ALPHA * dB * (dB + 0.9f));   // leg B start (k=10)
        float uB = EXP2F(14.4269504f * dB);            // 2^(0.2*ALPHA*dB)
        float uA = uB * E10;
        t[i] = f32x2{tA, tB};
        u[i] = f32x2{uA, uB};
        cnt += (dv[i] == qt) ? 1.0f : 0.0f;
    }
#pragma unroll
    for (int k = 0; k < 10; ++k) {
        ks2[k] += (t[0] + t[1]) + (t[2] + t[3]);       // tree: short dep chains
        t[0] *= u[0]; t[1] *= u[1]; t[2] *= u[2]; t[3] *= u[3];
    }
}

// ------------- kernel 2: barrier-free swapped-operand KNRM, 8-wave blocks -------------
// 1024 blocks (pair*b) x 512 threads. wave 0..6 = strip of 32 doc cols; wave 7 idle.
// mfma(D_frag, Q_frag): C/D col = lane&15 = QUERY row -> bank consumes the MFMA
// accumulators directly from registers. One barrier after token staging, one
// before the in-block finish.
__global__ __launch_bounds__(512, 4) void knrm_main(
    const ushort_t* __restrict__ nh, const float* __restrict__ W,
    const int* __restrict__ q1, const int* __restrict__ d1,
    const int* __restrict__ q2, const int* __restrict__ d2,
    float* __restrict__ logits)
{
    __shared__ int   sQtok[32];
    __shared__ __align__(16) int sDtok[256];
    __shared__ float kred[7][32][KN];              // 18816 B

    const int pb = blockIdx.x;
    const int pair = pb >> 9, b = pb & 511;
    const int* qind = (pair ? q2 : q1) + b * LQ;
    const int* dind = (pair ? d2 : d1) + b * RD;

    const int tid = threadIdx.x;
    const int lane = tid & 63, wave = tid >> 6;    // wave = strip (0..6), 7 idle
    const int r = lane & 15, g = lane >> 4;

    if (tid < 32)  sQtok[tid] = (tid < LQ) ? qind[tid] : -2;
    if (tid < 256) sDtok[tid] = (tid < RD) ? dind[tid] : -1;
    __syncthreads();

    if (wave < 7) {
        // ---- gathers: Q rows r / 16+r, D rows strip*32 + r / +16 ----
        const int qiA = qind[r];
        const int qiB = qind[(16 + r) < LQ ? (16 + r) : LQ - 1];
        const int dcA = wave * 32 + r, dcB = dcA + 16;
        const int diA = dind[dcA < RD ? dcA : RD - 1];
        const int diB = dind[dcB < RD ? dcB : RD - 1];

        int4 qa[4], qb[4], da[4], db[4];
        load_frag4(nh + (size_t)qiA * DIM + g * 8, qa);
        load_frag4(nh + (size_t)qiB * DIM + g * 8, qb);
        load_frag4(nh + (size_t)diA * DIM + g * 8, da);
        load_frag4(nh + (size_t)diB * DIM + g * 8, db);

        // ---- 16 MFMAs: acc rows = D cols (g*4+j), cols = Q rows (r) ----
        f32x4 a00 = {0.f,0.f,0.f,0.f}, a01 = {0.f,0.f,0.f,0.f};
        f32x4 a10 = {0.f,0.f,0.f,0.f}, a11 = {0.f,0.f,0.f,0.f};
#pragma unroll
        for (int ks = 0; ks < 4; ++ks) {
            bf16x8 fa = as_frag(da[ks]), fb = as_frag(db[ks]);
            bf16x8 f0 = as_frag(qa[ks]), f1 = as_frag(qb[ks]);
            a00 = __builtin_amdgcn_mfma_f32_16x16x32_bf16(fa, f0, a00, 0, 0, 0);
            a01 = __builtin_amdgcn_mfma_f32_16x16x32_bf16(fa, f1, a01, 0, 0, 0);
            a10 = __builtin_amdgcn_mfma_f32_16x16x32_bf16(fb, f0, a10, 0, 0, 0);
            a11 = __builtin_amdgcn_mfma_f32_16x16x32_bf16(fb, f1, a11, 0, 0, 0);
        }

        const int4* sDtok4 = (const int4*)sDtok;
        const int4 dtA = sDtok4[wave * 8 + g];     // cols strip*32 + g*4 + j
        const int4 dtB = sDtok4[wave * 8 + 4 + g]; // +16
        const int qt0 = sQtok[r], qt1 = sQtok[16 + r];
        const int colA = wave * 32 + g * 4, colB = colA + 16;

        // ---- rowgroup 0 (q rows 0..15) ----
        {
            f32x2 ks2[10];
#pragma unroll
            for (int k = 0; k < 10; ++k) ks2[k] = f32x2{0.f, 0.f};
            float cnt = 0.0f;
            bank4_pk(a00, dtA, qt0, colA, ks2, cnt);
            bank4_pk(a10, dtB, qt0, colB, ks2, cnt);
#pragma unroll
            for (int k = 0; k < 10; ++k) {
                float vA = ks2[k].x, vB = ks2[k].y;
                vA += __shfl_xor(vA, 16); vA += __shfl_xor(vA, 32);
                vB += __shfl_xor(vB, 16); vB += __shfl_xor(vB, 32);
                ks2[k] = f32x2{vA, vB};
            }
            cnt += __shfl_xor(cnt, 16); cnt += __shfl_xor(cnt, 32);
            if (lane < 16) {
#pragma unroll
                for (int k = 0; k < 10; ++k) {
                    kred[wave][r][k]      = ks2[k].x;
                    kred[wave][r][10 + k] = ks2[k].y;
                }
                kred[wave][r][20] = cnt;
            }
        }
        // ---- rowgroup 1 (q rows 16..31; 30,31 written but never read) ----
        {
            f32x2 ks2[10];
#pragma unroll
            for (int k = 0; k < 10; ++k) ks2[k] = f32x2{0.f, 0.f};
            float cnt = 0.0f;
            bank4_pk(a01, dtA, qt1, colA, ks2, cnt);
            bank4_pk(a11, dtB, qt1, colB, ks2, cnt);
#pragma unroll
            for (int k = 0; k < 10; ++k) {
                float vA = ks2[k].x, vB = ks2[k].y;
                vA += __shfl_xor(vA, 16); vA += __shfl_xor(vA, 32);
                vB += __shfl_xor(vB, 16); vB += __shfl_xor(vB, 32);
                ks2[k] = f32x2{vA, vB};
            }
            cnt += __shfl_xor(cnt, 16); cnt += __shfl_xor(cnt, 32);
            if (lane < 16) {
#pragma unroll
                for (int k = 0; k < 10; ++k) {
                    kred[wave][16 + r][k]      = ks2[k].x;
                    kred[wave][16 + r][10 + k] = ks2[k].y;
                }
                kred[wave][16 + r][20] = cnt;
            }
        }
    }
    __syncthreads();

    // ---- finish: combine strips, B_j scale, log1p, W-dot, row reduce ----
    if (tid < 32) {
        float part = 0.0f;
        if (tid < LQ) {
#pragma unroll
            for (int k = 0; k < KN; ++k) {
                float s = 0.0f;
#pragma unroll
                for (int st = 0; st < 7; ++st) s += kred[st][tid][k];
                float sc = 1.0f;
                if (k < 20) {
                    float j = (float)((k < 10) ? k : k - 10) - 4.5f;
                    sc = EXP2F(-0.721347520f * j * j);   // B_j (compile-time)
                }
                part += W[k] * log1pf(sc * s);
            }
        }
        part += __shfl_xor(part, 1);
        part += __shfl_xor(part, 2);
        part += __shfl_xor(part, 4);
        part += __shfl_xor(part, 8);
        part += __shfl_xor(part, 16);
        if (tid == 0) logits[pair * BB + b] = part;   // bias cancels in diff
    }
}

// ------------- kernel 3: sigmoid of logit difference -------------
__global__ void knrm_final(const float* __restrict__ logits, float* __restrict__ out) {
    int i = blockIdx.x * blockDim.x + threadIdx.x;
    if (i < BB) {
        float x = logits[i] - logits[BB + i];
        out[i] = 1.0f / (1.0f + expf(-x));
    }
}

extern "C" void kernel_launch(void* const* d_in, const int* in_sizes, int n_in,
                              void* d_out, int out_size, void* d_ws, size_t ws_size,
                              hipStream_t stream) {
    const float* emb = (const float*)d_in[0];
    const float* W   = (const float*)d_in[1];
    const int* q1    = (const int*)d_in[3];
    const int* dd1   = (const int*)d_in[4];
    const int* q2    = (const int*)d_in[5];
    const int* dd2   = (const int*)d_in[6];

    ushort_t* nh  = (ushort_t*)d_ws;                 // V*128 bf16 = 12.8 MB
    float* logits = (float*)(nh + (size_t)V * DIM);  // 1024 floats

    knrm_norm<<<V / 8, 256, 0, stream>>>(emb, nh);
    knrm_main<<<1024, 512, 0, stream>>>(nh, W, q1, dd1, q2, dd2, logits);
    knrm_final<<<2, 256, 0, stream>>>(logits, (float*)d_out);
}

// Round 9
// 41.383 us; speedup vs baseline: 1.1536x; 1.1209x over previous
//
#include <hip/hip_runtime.h>
#include <math.h>

#define V   50000
#define DIM 128
#define BB  512
#define LQ  30
#define RD  200
#define KN  21

typedef unsigned short ushort_t;
typedef __attribute__((ext_vector_type(8))) short bf16x8;   // 8 bf16 = 4 VGPRs
typedef __attribute__((ext_vector_type(4))) float f32x4;
typedef __attribute__((ext_vector_type(2))) float f32x2;    // -> v_pk_*_f32

#if __has_builtin(__builtin_amdgcn_exp2f)
#define EXP2F(x) __builtin_amdgcn_exp2f(x)
#else
#define EXP2F(x) __expf((x) * 0.69314718f)
#endif

#define ALPHA 72.1347520f       // 50 * log2(e)
#define E10   22026.4657948f    // 2^(0.2*ALPHA) = e^10

static __device__ __forceinline__ ushort_t f2bf(float x) {
    unsigned u = __builtin_bit_cast(unsigned, x);
    return (ushort_t)((u + 0x7FFFu + ((u >> 16) & 1u)) >> 16);   // RNE
}
static __device__ __forceinline__ bf16x8 as_frag(int4 v) {
    return __builtin_bit_cast(bf16x8, v);
}

// ------------- kernel 1: L2-normalize -> bf16 (hi only), float4 loads -------------
__global__ __launch_bounds__(256) void knrm_norm(const float* __restrict__ emb,
                                                 ushort_t* __restrict__ nh) {
    int row = blockIdx.x * 8 + (threadIdx.x >> 5);   // V divisible by 8
    int c4  = (threadIdx.x & 31) * 4;
    const float4 v = *reinterpret_cast<const float4*>(emb + (size_t)row * DIM + c4);
    float ss = v.x * v.x + v.y * v.y + v.z * v.z + v.w * v.w;
#pragma unroll
    for (int off = 1; off < 32; off <<= 1) ss += __shfl_xor(ss, off);
    float inv = 1.0f / fmaxf(sqrtf(ss), 1e-12f);
    uint2 o;
    o.x = (unsigned)f2bf(v.x * inv) | ((unsigned)f2bf(v.y * inv) << 16);
    o.y = (unsigned)f2bf(v.z * inv) | ((unsigned)f2bf(v.w * inv) << 16);
    *reinterpret_cast<uint2*>(nh + (size_t)row * DIM + c4) = o;
}

// Two-leg geometric Gaussian bank (verified R6), packed f32x2 (x = leg A,
// kernels 0..9 center mu=-0.5; y = leg B, 10..19 center +0.5), 4 independent
// t*u chains with tree summation. B_j folded in at the partial store.
// Exact kernel (mu=1, sigma=1e-3) = integer token equality count.
// NOTE: no per-element col mask — RD=200 and quad bases are 4-aligned, so the
// 32-granular call-site guards cover every quad exactly.
static __device__ __forceinline__ void bank4_pk(float4 pv, int4 dt, int qt,
                                                f32x2* ks2, float& cnt) {
    const float mv[4] = {pv.x, pv.y, pv.z, pv.w};
    const int   dv[4] = {dt.x, dt.y, dt.z, dt.w};
    f32x2 t[4], u[4];
#pragma unroll
    for (int i = 0; i < 4; ++i) {
        float m  = mv[i];
        float dA = m + 0.5f, dB = m - 0.5f;
        float tA = EXP2F(-ALPHA * dA * (dA + 0.9f));   // leg A start (k=0)
        float tB = EXP2F(-ALPHA * dB * (dB + 0.9f));   // leg B start (k=10)
        float uB = EXP2F(14.4269504f * dB);            // 2^(0.2*ALPHA*dB)
        float uA = uB * E10;
        t[i] = f32x2{tA, tB};
        u[i] = f32x2{uA, uB};
        cnt += (dv[i] == qt) ? 1.0f : 0.0f;
    }
#pragma unroll
    for (int k = 0; k < 10; ++k) {
        ks2[k] += (t[0] + t[1]) + (t[2] + t[3]);       // tree: short dep chains
        t[0] *= u[0]; t[1] *= u[1]; t[2] *= u[2]; t[3] *= u[3];
    }
}

static __device__ __forceinline__ void load_frag4(const ushort_t* base, int4* f) {
    f[0] = *reinterpret_cast<const int4*>(base);
    f[1] = *reinterpret_cast<const int4*>(base + 32);
    f[2] = *reinterpret_cast<const int4*>(base + 64);
    f[3] = *reinterpret_cast<const int4*>(base + 96);
}

// ------------- kernel 2: gather-direct MFMA + packed geometric bank, y-split -------------
// (R6 structure verbatim: grid (1024,2) x 256 thr, no staging LDS, T14 prefetch)
__global__ __launch_bounds__(256) void knrm_main(
    const ushort_t* __restrict__ nh,
    const int* __restrict__ q1, const int* __restrict__ d1,
    const int* __restrict__ q2, const int* __restrict__ d2,
    float* __restrict__ partial)
{
    __shared__ __align__(16) char smem[10752];
    float (*P)[68] = reinterpret_cast<float (*)[68]>(smem);   // 32x68 f32
    float* kredw   = reinterpret_cast<float*>(smem);          // 4x32x21 f32
    __shared__ int sQtok[32];
    __shared__ int sDtok[128];

    const int pb = blockIdx.x, y = blockIdx.y;
    const int pair = pb >> 9, b = pb & 511;
    const int* qind = (pair ? q2 : q1) + b * LQ;
    const int* dind = (pair ? d2 : d1) + b * RD;
    const int cb = y * 128;

    const int tid = threadIdx.x;
    const int lane = tid & 63, wave = tid >> 6;
    const int r = lane & 15, g = lane >> 4;
    const int rt = wave & 1, half = wave >> 1;

    if (tid < 32)  sQtok[tid] = (tid < LQ) ? qind[tid] : -2;
    if (tid < 128) { int c = cb + tid; sDtok[tid] = (c < RD) ? dind[c] : -1; }

    // ---- Q frags once into regs ----
    const int qrow = rt * 16 + r;
    const int qi = qind[qrow < LQ ? qrow : LQ - 1];
    int4 qh[4];
    load_frag4(nh + (size_t)qi * DIM + g * 8, qh);

    const int c64_0 = cb, c64_1 = cb + 64;
    const int dr0a = c64_0 + half * 32 + r,  dr0b = dr0a + 16;
    const int dr1a = c64_1 + half * 32 + r,  dr1b = dr1a + 16;
    const int di0a = dind[dr0a < RD ? dr0a : RD - 1];
    const int di0b = dind[dr0b < RD ? dr0b : RD - 1];

    f32x2 ks2[10];   // x = leg A (k 0..9), y = leg B (k 10..19)
#pragma unroll
    for (int k = 0; k < 10; ++k) ks2[k] = f32x2{0.f, 0.f};
    float cnt = 0.0f;

    const int brow = tid & 31;         // bank row
    const int c0   = (tid >> 5) * 4;   // bank quad base col (0..28)
    const int prow0 = rt * 16 + g * 4;

    // ================== tile 0 ==================
    {
        int4 d0[4], d1[4];
        load_frag4(nh + (size_t)di0a * DIM + g * 8, d0);
        load_frag4(nh + (size_t)di0b * DIM + g * 8, d1);
        f32x4 acc0 = {0.f, 0.f, 0.f, 0.f}, acc1 = {0.f, 0.f, 0.f, 0.f};
#pragma unroll
        for (int ks = 0; ks < 4; ++ks) {
            bf16x8 ah = as_frag(qh[ks]);
            acc0 = __builtin_amdgcn_mfma_f32_16x16x32_bf16(ah, as_frag(d0[ks]), acc0, 0, 0, 0);
            acc1 = __builtin_amdgcn_mfma_f32_16x16x32_bf16(ah, as_frag(d1[ks]), acc1, 0, 0, 0);
        }
        // C/D layout: col = lane&15, row = (lane>>4)*4 + j
#pragma unroll
        for (int j = 0; j < 4; ++j) {
            P[prow0 + j][half * 32 + r]      = acc0[j];
            P[prow0 + j][half * 32 + 16 + r] = acc1[j];
        }
    }
    __syncthreads();                           // P(0) visible

    // ---- T14: issue tile-1 D gathers before bank(0) ----
    int4 e0[4], e1[4];
    {
        const int di1a = dind[dr1a < RD ? dr1a : RD - 1];
        const int di1b = dind[dr1b < RD ? dr1b : RD - 1];
        load_frag4(nh + (size_t)di1a * DIM + g * 8, e0);
        load_frag4(nh + (size_t)di1b * DIM + g * 8, e1);
    }

    // ---- bank(0) ----
    if (brow < LQ && c64_0 + c0 < RD) {
        const int qt = sQtok[brow];
        float4 p0 = *reinterpret_cast<const float4*>(&P[brow][c0]);
        int4  dt0 = *reinterpret_cast<const int4*>(&sDtok[c0]);
        bank4_pk(p0, dt0, qt, ks2, cnt);
        if (c64_0 + c0 + 32 < RD) {
            float4 p1 = *reinterpret_cast<const float4*>(&P[brow][c0 + 32]);
            int4  dt1 = *reinterpret_cast<const int4*>(&sDtok[c0 + 32]);
            bank4_pk(p1, dt1, qt, ks2, cnt);
        }
    }

    // ================== tile 1 ==================
    f32x4 acc0 = {0.f, 0.f, 0.f, 0.f}, acc1 = {0.f, 0.f, 0.f, 0.f};
#pragma unroll
    for (int ks = 0; ks < 4; ++ks) {
        bf16x8 ah = as_frag(qh[ks]);
        acc0 = __builtin_amdgcn_mfma_f32_16x16x32_bf16(ah, as_frag(e0[ks]), acc0, 0, 0, 0);
        acc1 = __builtin_amdgcn_mfma_f32_16x16x32_bf16(ah, as_frag(e1[ks]), acc1, 0, 0, 0);
    }
    __syncthreads();                           // bank(0) P reads done
#pragma unroll
    for (int j = 0; j < 4; ++j) {
        P[prow0 + j][half * 32 + r]      = acc0[j];
        P[prow0 + j][half * 32 + 16 + r] = acc1[j];
    }
    __syncthreads();                           // P(1) visible

    if (brow < LQ && c64_1 + c0 < RD) {
        const int qt = sQtok[brow];
        float4 p0 = *reinterpret_cast<const float4*>(&P[brow][c0]);
        int4  dt0 = *reinterpret_cast<const int4*>(&sDtok[64 + c0]);
        bank4_pk(p0, dt0, qt, ks2, cnt);
        if (c64_1 + c0 + 32 < RD) {
            float4 p1 = *reinterpret_cast<const float4*>(&P[brow][c0 + 32]);
            int4  dt1 = *reinterpret_cast<const int4*>(&sDtok[64 + c0 + 32]);
            bank4_pk(p1, dt1, qt, ks2, cnt);
        }
    }
    __syncthreads();                           // P dead -> smem = kredw

    // ---- reduce: quad-pairs via xor32, cross-wave via LDS ----
#pragma unroll
    for (int k = 0; k < 10; ++k) {
        float va = ks2[k].x + __shfl_xor(ks2[k].x, 32);
        float vb = ks2[k].y + __shfl_xor(ks2[k].y, 32);
        ks2[k] = f32x2{va, vb};
    }
    cnt += __shfl_xor(cnt, 32);
    if (lane < 32) {
        const int base = (wave * 32 + lane) * KN;
#pragma unroll
        for (int k = 0; k < 10; ++k) {
            kredw[base + k]      = ks2[k].x;
            kredw[base + 10 + k] = ks2[k].y;
        }
        kredw[base + 20] = cnt;
    }
    __syncthreads();

    // store partials, folding in the per-kernel B_j constant
    float* dst = partial + ((size_t)pb * 2 + y) * (LQ * KN);
    for (int e = tid; e < LQ * KN; e += 256) {
        int row = e / KN, k = e - row * KN;
        float s = kredw[row * KN + k] + kredw[(32 + row) * KN + k]
                + kredw[(64 + row) * KN + k] + kredw[(96 + row) * KN + k];
        float sc = 1.0f;
        if (k < 20) {
            float j = (float)((k < 10) ? k : k - 10) - 4.5f;
            sc = EXP2F(-0.721347520f * j * j);     // B_j = 2^(-0.01*ALPHA*j^2)
        }
        dst[e] = sc * s;
    }
}

// ------------- kernel 3: combine halves, log1p, W-dot, diff, sigmoid -------------
__global__ __launch_bounds__(128) void knrm_finish(const float* __restrict__ partial,
                                                   const float* __restrict__ W,
                                                   float* __restrict__ out) {
    __shared__ float red[2];
    const int b = blockIdx.x, tid = threadIdx.x;
    float s = 0.0f;
    for (int e = tid; e < LQ * KN; e += 128) {
        int row = e / KN, k = e - row * KN;
        float s1 = partial[((size_t)b * 2 + 0) * (LQ * KN) + e]
                 + partial[((size_t)b * 2 + 1) * (LQ * KN) + e];
        float s2 = partial[((size_t)(BB + b) * 2 + 0) * (LQ * KN) + e]
                 + partial[((size_t)(BB + b) * 2 + 1) * (LQ * KN) + e];
        s += W[k] * (log1pf(s1) - log1pf(s2));
    }
#pragma unroll
    for (int off = 1; off < 64; off <<= 1) s += __shfl_xor(s, off);
    if ((tid & 63) == 0) red[tid >> 6] = s;
    __syncthreads();
    if (tid == 0) {
        float logit = red[0] + red[1];   // bias cancels in the difference
        out[b] = 1.0f / (1.0f + expf(-logit));
    }
}

extern "C" void kernel_launch(void* const* d_in, const int* in_sizes, int n_in,
                              void* d_out, int out_size, void* d_ws, size_t ws_size,
                              hipStream_t stream) {
    const float* emb = (const float*)d_in[0];
    const float* W   = (const float*)d_in[1];
    const int* q1    = (const int*)d_in[3];
    const int* dd1   = (const int*)d_in[4];
    const int* q2    = (const int*)d_in[5];
    const int* dd2   = (const int*)d_in[6];

    float* partial = (float*)d_ws;                          // 2048*630 f32 = 5.16 MB
    ushort_t* nh   = (ushort_t*)(partial + 2048 * LQ * KN); // V*128 bf16 = 12.8 MB

    knrm_norm<<<V / 8, 256, 0, stream>>>(emb, nh);
    dim3 grid(1024, 2);
    knrm_main<<<grid, 256, 0, stream>>>(nh, q1, dd1, q2, dd2, partial);
    knrm_finish<<<BB, 128, 0, stream>>>(partial, W, (float*)d_out);
}